// Round 1
// baseline (588.042 us; speedup 1.0000x reference)
//
#include <hip/hip_runtime.h>
#include <math.h>

#define D_MODEL 256
#define NHEAD   8
#define NLVL    4
#define NPTS    4
#define DHEAD   32
#define DFFN    1024
#define NQ      900
#define BSZ     4
#define NROW    (NQ * BSZ)      // 3600
#define S_TOT   11253
#define VROWS   (S_TOT * BSZ)   // 45012

// ---------------------------------------------------------------------------
// Generic tiled fp32 GEMM:  C[m,n] = sum_k A[m,k] * W[n,k] + bias[n]
// A: M x K (row-major, ld=K), W: N x K (row-major, ld=K), C: M x ldc.
// N must be a multiple of 64 and K a multiple of 32 (true for all calls here).
// ---------------------------------------------------------------------------
#define BM 64
#define BN 64
#define BK 32
#define LDS_PAD (BM + 4)   // 68 floats: 16B-aligned float4 rows, broken bank stride

__global__ __launch_bounds__(256) void gemm_nt(
    const float* __restrict__ A, const float* __restrict__ W,
    const float* __restrict__ bias, float* __restrict__ C,
    int M, int N, int K, int ldc, int relu)
{
    __shared__ float As[BK][LDS_PAD];
    __shared__ float Ws[BK][LDS_PAD];

    const int t  = threadIdx.x;
    const int m0 = blockIdx.x * BM;
    const int n0 = blockIdx.y * BN;
    const int lr = t >> 3;          // 0..31 (row within half-tile)
    const int lc = (t & 7) << 2;    // 0,4,...,28 (k offset)
    const int tx = t & 15;          // col group
    const int ty = t >> 4;          // row group

    float acc[4][4] = {};

    for (int k0 = 0; k0 < K; k0 += BK) {
#pragma unroll
        for (int r = 0; r < BM; r += 32) {
            int m = m0 + lr + r;
            float4 va = make_float4(0.f, 0.f, 0.f, 0.f);
            if (m < M) va = *(const float4*)(A + (size_t)m * K + k0 + lc);
            As[lc + 0][lr + r] = va.x;
            As[lc + 1][lr + r] = va.y;
            As[lc + 2][lr + r] = va.z;
            As[lc + 3][lr + r] = va.w;
            int n = n0 + lr + r;   // always < N (N multiple of 64)
            float4 vw = *(const float4*)(W + (size_t)n * K + k0 + lc);
            Ws[lc + 0][lr + r] = vw.x;
            Ws[lc + 1][lr + r] = vw.y;
            Ws[lc + 2][lr + r] = vw.z;
            Ws[lc + 3][lr + r] = vw.w;
        }
        __syncthreads();
#pragma unroll
        for (int kk = 0; kk < BK; ++kk) {
            float4 a4 = *(const float4*)&As[kk][ty << 2];
            float4 w4 = *(const float4*)&Ws[kk][tx << 2];
            float av[4] = {a4.x, a4.y, a4.z, a4.w};
            float wv[4] = {w4.x, w4.y, w4.z, w4.w};
#pragma unroll
            for (int i = 0; i < 4; ++i)
#pragma unroll
                for (int j = 0; j < 4; ++j)
                    acc[i][j] = fmaf(av[i], wv[j], acc[i][j]);
        }
        __syncthreads();
    }

    float4 bv = *(const float4*)(bias + n0 + (tx << 2));
    float bb[4] = {bv.x, bv.y, bv.z, bv.w};
#pragma unroll
    for (int i = 0; i < 4; ++i) {
        int m = m0 + (ty << 2) + i;
        if (m >= M) continue;
        float4 o;
        o.x = acc[i][0] + bb[0];
        o.y = acc[i][1] + bb[1];
        o.z = acc[i][2] + bb[2];
        o.w = acc[i][3] + bb[3];
        if (relu) {
            o.x = fmaxf(o.x, 0.f); o.y = fmaxf(o.y, 0.f);
            o.z = fmaxf(o.z, 0.f); o.w = fmaxf(o.w, 0.f);
        }
        *(float4*)(C + (size_t)m * ldc + n0 + (tx << 2)) = o;
    }
}

// ---------------------------------------------------------------------------
// Elementwise add (float4): c = a + b
// ---------------------------------------------------------------------------
__global__ void add_vec(const float* __restrict__ a, const float* __restrict__ b,
                        float* __restrict__ c, int n4)
{
    int i = blockIdx.x * blockDim.x + threadIdx.x;
    if (i < n4) {
        float4 x = ((const float4*)a)[i];
        float4 y = ((const float4*)b)[i];
        float4 z;
        z.x = x.x + y.x; z.y = x.y + y.y; z.z = x.z + y.z; z.w = x.w + y.w;
        ((float4*)c)[i] = z;
    }
}

// ---------------------------------------------------------------------------
// Self-attention.  qkv: (3600, 768) rows=(q*4+b), cols=[q(256)|k(256)|v(256)].
// One block per (q-tile of 32, b, h).  2-pass online softmax, K/V staged LDS.
// out: (3600, 256) rows=(q*4+b), cols=h*32+d
// ---------------------------------------------------------------------------
#define KT 64
#define KSTRIDE 36   // LDS row stride for K/V tiles (16B aligned, bank-spread)

__global__ __launch_bounds__(256) void sa_kernel(
    const float* __restrict__ qkv, float* __restrict__ attn_out)
{
    const int t  = threadIdx.x;
    const int q0 = blockIdx.x * 32;
    const int bh = blockIdx.y;
    const int b  = bh & 3;
    const int h  = bh >> 2;
    const int ql = t & 31;
    const int g  = t >> 5;        // 0..7
    const int q  = q0 + ql;
    const bool qvalid = (q < NQ);

    __shared__ float smem[9216];          // Ks[64][36] | Vs[64][36]; overlay opart[8][32][36]
    float* Ks = smem;
    float* Vs = smem + KT * KSTRIDE;      // +2304
    __shared__ float mred[8][32];
    __shared__ float lred[8][32];
    __shared__ float msh[32];
    __shared__ float lish[32];

    // load Q row into registers
    float qr[32];
    const float* qbase = qkv + ((size_t)q * 4 + b) * 768 + h * 32;
#pragma unroll
    for (int d4 = 0; d4 < 32; d4 += 4) {
        float4 v = qvalid ? *(const float4*)(qbase + d4) : make_float4(0.f, 0.f, 0.f, 0.f);
        qr[d4 + 0] = v.x; qr[d4 + 1] = v.y; qr[d4 + 2] = v.z; qr[d4 + 3] = v.w;
    }
    const float scale = 0.17677669529663687f;  // 1/sqrt(32)

    // ---- pass A: per-thread online (max, sumexp) over strided keys ----
    float m_t = -1e30f, l_t = 0.f;
    for (int k0 = 0; k0 < NQ; k0 += KT) {
        int kmax = NQ - k0; if (kmax > KT) kmax = KT;
        for (int i = t; i < 512; i += 256) {        // 512 float4 = 64x32 tile
            int krow = i >> 3, c4 = (i & 7) << 2;
            float4 kv = make_float4(0.f, 0.f, 0.f, 0.f);
            if (krow < kmax)
                kv = *(const float4*)(qkv + ((size_t)(k0 + krow) * 4 + b) * 768 + 256 + h * 32 + c4);
            *(float4*)&Ks[krow * KSTRIDE + c4] = kv;
        }
        __syncthreads();
        for (int kk = g; kk < kmax; kk += 8) {
            float s = 0.f;
#pragma unroll
            for (int d4 = 0; d4 < 32; d4 += 4) {
                float4 kv = *(const float4*)&Ks[kk * KSTRIDE + d4];
                s = fmaf(qr[d4 + 0], kv.x, s);
                s = fmaf(qr[d4 + 1], kv.y, s);
                s = fmaf(qr[d4 + 2], kv.z, s);
                s = fmaf(qr[d4 + 3], kv.w, s);
            }
            s *= scale;
            float mn = fmaxf(m_t, s);
            l_t = l_t * __expf(m_t - mn) + __expf(s - mn);
            m_t = mn;
        }
        __syncthreads();
    }
    mred[g][ql] = m_t;
    lred[g][ql] = l_t;
    __syncthreads();
    if (t < 32) {
        float m = mred[0][t];
#pragma unroll
        for (int i = 1; i < 8; ++i) m = fmaxf(m, mred[i][t]);
        float l = 0.f;
#pragma unroll
        for (int i = 0; i < 8; ++i) l += lred[i][t] * __expf(mred[i][t] - m);
        msh[t] = m;
        lish[t] = 1.f / l;
    }
    __syncthreads();
    const float mq  = msh[ql];
    const float liq = lish[ql];

    // ---- pass B: recompute scores, accumulate P*V ----
    float acc[32] = {};
    for (int k0 = 0; k0 < NQ; k0 += KT) {
        int kmax = NQ - k0; if (kmax > KT) kmax = KT;
        for (int i = t; i < 512; i += 256) {
            int krow = i >> 3, c4 = (i & 7) << 2;
            float4 kv = make_float4(0.f, 0.f, 0.f, 0.f);
            float4 vv = make_float4(0.f, 0.f, 0.f, 0.f);
            if (krow < kmax) {
                const float* base = qkv + ((size_t)(k0 + krow) * 4 + b) * 768 + 256 + h * 32 + c4;
                kv = *(const float4*)base;
                vv = *(const float4*)(base + 256);
            }
            *(float4*)&Ks[krow * KSTRIDE + c4] = kv;
            *(float4*)&Vs[krow * KSTRIDE + c4] = vv;
        }
        __syncthreads();
        for (int kk = g; kk < kmax; kk += 8) {
            float s = 0.f;
#pragma unroll
            for (int d4 = 0; d4 < 32; d4 += 4) {
                float4 kv = *(const float4*)&Ks[kk * KSTRIDE + d4];
                s = fmaf(qr[d4 + 0], kv.x, s);
                s = fmaf(qr[d4 + 1], kv.y, s);
                s = fmaf(qr[d4 + 2], kv.z, s);
                s = fmaf(qr[d4 + 3], kv.w, s);
            }
            s *= scale;
            float p = __expf(s - mq) * liq;
#pragma unroll
            for (int d4 = 0; d4 < 32; d4 += 4) {
                float4 vv = *(const float4*)&Vs[kk * KSTRIDE + d4];
                acc[d4 + 0] = fmaf(p, vv.x, acc[d4 + 0]);
                acc[d4 + 1] = fmaf(p, vv.y, acc[d4 + 1]);
                acc[d4 + 2] = fmaf(p, vv.z, acc[d4 + 2]);
                acc[d4 + 3] = fmaf(p, vv.w, acc[d4 + 3]);
            }
        }
        __syncthreads();
    }

    // reduce the 8 strided partials (overlay the K/V staging memory)
    float* opart = smem;   // [8][32][36]
#pragma unroll
    for (int d4 = 0; d4 < 32; d4 += 4)
        *(float4*)&opart[g * 1152 + ql * 36 + d4] =
            make_float4(acc[d4], acc[d4 + 1], acc[d4 + 2], acc[d4 + 3]);
    __syncthreads();
#pragma unroll
    for (int j = 0; j < 4; ++j) {
        int idx = t + j * 256;
        int qq = idx >> 5, dd = idx & 31;
        float s = 0.f;
#pragma unroll
        for (int gg = 0; gg < 8; ++gg) s += opart[gg * 1152 + qq * 36 + dd];
        if (q0 + qq < NQ)
            attn_out[((size_t)(q0 + qq) * 4 + b) * 256 + h * 32 + dd] = s;
    }
}

// ---------------------------------------------------------------------------
// Residual + LayerNorm (optionally also emits y + pos into out2).
// row layout: (q*4+b) x 256. One block per row, 256 threads.
// ---------------------------------------------------------------------------
__global__ __launch_bounds__(256) void ln_resid(
    const float* __restrict__ xa, const float* __restrict__ xb,
    const float* __restrict__ gam, const float* __restrict__ bet,
    float* __restrict__ out, const float* __restrict__ pos, float* __restrict__ out2)
{
    const int row = blockIdx.x;
    const int t = threadIdx.x;
    float x = xa[(size_t)row * D_MODEL + t] + xb[(size_t)row * D_MODEL + t];
    float s = x, s2 = x * x;
#pragma unroll
    for (int off = 32; off > 0; off >>= 1) {
        s  += __shfl_down(s, off, 64);
        s2 += __shfl_down(s2, off, 64);
    }
    __shared__ float rs[4], rs2[4];
    __shared__ float mean_s, rstd_s;
    int wid = t >> 6, lane = t & 63;
    if (lane == 0) { rs[wid] = s; rs2[wid] = s2; }
    __syncthreads();
    if (t == 0) {
        float S = rs[0] + rs[1] + rs[2] + rs[3];
        float S2 = rs2[0] + rs2[1] + rs2[2] + rs2[3];
        float mean = S * (1.f / 256.f);
        float var = S2 * (1.f / 256.f) - mean * mean;
        mean_s = mean;
        rstd_s = rsqrtf(var + 1e-5f);
    }
    __syncthreads();
    float y = (x - mean_s) * rstd_s * gam[t] + bet[t];
    out[(size_t)row * D_MODEL + t] = y;
    if (out2) out2[(size_t)row * D_MODEL + t] = y + pos[(size_t)row * D_MODEL + t];
}

// ---------------------------------------------------------------------------
// Multi-scale deformable sampling.
// off_raw: (3600,256) rows=(q*4+b), col=((h*4+l)*4+p)*2+c
// aw_raw:  (3600,128) col=h*16+(l*4+p)   (pre-softmax logits)
// refp:    (900,4,4,2)
// value:   rows=(s*4+b), cols=h*32+d  -> flat index s*1024 + b*256 + h*32 + d
// out:     (3600,256) rows=(q*4+b)
// One block per (q,b); thread t -> (h = t/32, d = t%32).
// ---------------------------------------------------------------------------
__global__ __launch_bounds__(256) void msdeform_kernel(
    const float* __restrict__ off_raw, const float* __restrict__ aw_raw,
    const float* __restrict__ refp, const float* __restrict__ value,
    float* __restrict__ out)
{
    const int row = blockIdx.x;   // q*4+b
    const int b = row & 3;
    const int t = threadIdx.x;

    __shared__ float aw_s[8][17];
    __shared__ float px_s[8][16];
    __shared__ float py_s[8][16];

    const int Hs[4]  = {92, 46, 23, 12};
    const int Wd[4]  = {92, 46, 23, 12};
    const int S0_[4] = {0, 8464, 10580, 11109};

    if (t < 128) {
        int hh = t >> 4, lp = t & 15, l = lp >> 2;
        float ox = off_raw[(size_t)row * 256 + hh * 32 + lp * 2 + 0];
        float oy = off_raw[(size_t)row * 256 + hh * 32 + lp * 2 + 1];
        float rx = refp[((size_t)row * 4 + l) * 2 + 0];
        float ry = refp[((size_t)row * 4 + l) * 2 + 1];
        // px = (rx + ox/W)*W - 0.5 = rx*W + ox - 0.5
        px_s[hh][lp] = rx * (float)Wd[l] + ox - 0.5f;
        py_s[hh][lp] = ry * (float)Hs[l] + oy - 0.5f;
    }
    if (t < 8) {
        int hh = t;
        float v[16];
        float m = -1e30f;
#pragma unroll
        for (int j = 0; j < 16; ++j) {
            v[j] = aw_raw[(size_t)row * 128 + hh * 16 + j];
            m = fmaxf(m, v[j]);
        }
        float ssum = 0.f;
#pragma unroll
        for (int j = 0; j < 16; ++j) { v[j] = __expf(v[j] - m); ssum += v[j]; }
        float inv = 1.f / ssum;
#pragma unroll
        for (int j = 0; j < 16; ++j) aw_s[hh][j] = v[j] * inv;
    }
    __syncthreads();

    const int h = t >> 5, d = t & 31;
    const float* vb = value + (size_t)b * 256 + h * 32 + d;
    float acc = 0.f;
#pragma unroll
    for (int l = 0; l < 4; ++l) {
        const int H = Hs[l], W = Wd[l], base = S0_[l];
#pragma unroll
        for (int p = 0; p < 4; ++p) {
            const int lp = l * 4 + p;
            float px = px_s[h][lp], py = py_s[h][lp];
            float x0f = floorf(px), y0f = floorf(py);
            int x0 = (int)x0f, y0 = (int)y0f;
            float wx = px - x0f, wy = py - y0f;
            float sv = 0.f;
#pragma unroll
            for (int dy = 0; dy < 2; ++dy) {
#pragma unroll
                for (int dx = 0; dx < 2; ++dx) {
                    int xi = x0 + dx, yi = y0 + dy;
                    float flag = (xi >= 0 && xi < W && yi >= 0 && yi < H) ? 1.f : 0.f;
                    int xc = xi < 0 ? 0 : (xi >= W ? W - 1 : xi);
                    int yc = yi < 0 ? 0 : (yi >= H ? H - 1 : yi);
                    float wgt = (dx ? wx : 1.f - wx) * (dy ? wy : 1.f - wy);
                    float gv = vb[(size_t)(base + yc * W + xc) * 1024];
                    sv = fmaf(wgt * flag, gv, sv);
                }
            }
            acc = fmaf(aw_s[h][lp], sv, acc);
        }
    }
    out[(size_t)row * 256 + h * 32 + d] = acc;
}

// ---------------------------------------------------------------------------
extern "C" void kernel_launch(void* const* d_in, const int* in_sizes, int n_in,
                              void* d_out, int out_size, void* d_ws, size_t ws_size,
                              hipStream_t stream)
{
    const float* tgt    = (const float*)d_in[0];
    const float* qpos   = (const float*)d_in[1];
    const float* refp   = (const float*)d_in[2];
    const float* mem    = (const float*)d_in[3];
    // d_in[4], d_in[5]: spatial shapes / level starts (hardcoded as constants)
    const float* in_w   = (const float*)d_in[6];
    const float* in_b   = (const float*)d_in[7];
    const float* outp_w = (const float*)d_in[8];
    const float* outp_b = (const float*)d_in[9];
    const float* off_w  = (const float*)d_in[10];
    const float* off_b  = (const float*)d_in[11];
    const float* aw_w   = (const float*)d_in[12];
    const float* aw_b   = (const float*)d_in[13];
    const float* vp_w   = (const float*)d_in[14];
    const float* vp_b   = (const float*)d_in[15];
    const float* op_w   = (const float*)d_in[16];
    const float* op_b   = (const float*)d_in[17];
    const float* ln1g   = (const float*)d_in[18];
    const float* ln1b   = (const float*)d_in[19];
    const float* ln2g   = (const float*)d_in[20];
    const float* ln2b   = (const float*)d_in[21];
    const float* ln3g   = (const float*)d_in[22];
    const float* ln3b   = (const float*)d_in[23];
    const float* l1w    = (const float*)d_in[24];
    const float* l1b    = (const float*)d_in[25];
    const float* l2w    = (const float*)d_in[26];
    const float* l2b    = (const float*)d_in[27];
    float* out = (float*)d_out;
    float* ws  = (float*)d_ws;

    // workspace layout (floats); total 18,895,872 floats = 75.6 MB
    float* qkv     = ws;                 // 3600*768 = 2,764,800
    float* off_raw = ws;                 // reuse of qkv region (after SA done)
    float* aw_raw  = ws + 921600;        //   "
    float* xq      = ws + 2764800;       // 921,600 (later: xca)
    float* att     = ws + 3686400;       // 921,600 (attn_out; later: ca sampled out)
    float* tmp     = ws + 4608000;       // 921,600 (proj scratch)
    float* tgt_a   = ws + 5529600;       // 921,600
    float* tgt_b   = ws + 6451200;       // 921,600
    float* value   = ws + 7372800;       // 45012*256 = 11,523,072
    float* hidden  = value;              // reuse after sampling (3600*1024)

    dim3 b256(256);

    // 1. xq = tgt + qpos
    hipLaunchKernelGGL(add_vec, dim3(900), b256, 0, stream, tgt, qpos, xq, 230400);
    // 2. qkv[:, 0:512] = xq @ [wq;wk]^T + b
    hipLaunchKernelGGL(gemm_nt, dim3(57, 8), b256, 0, stream,
                       xq, in_w, in_b, qkv, NROW, 512, 256, 768, 0);
    // 3. qkv[:, 512:768] = tgt @ wv^T + bv
    hipLaunchKernelGGL(gemm_nt, dim3(57, 4), b256, 0, stream,
                       tgt, in_w + 512 * 256, in_b + 512, qkv + 512, NROW, 256, 256, 768, 0);
    // 4. self-attention
    hipLaunchKernelGGL(sa_kernel, dim3(29, 32), b256, 0, stream, qkv, att);
    // 5. attention out-proj
    hipLaunchKernelGGL(gemm_nt, dim3(57, 4), b256, 0, stream,
                       att, outp_w, outp_b, tmp, NROW, 256, 256, 256, 0);
    // 6. tgt_a = LN2(tgt + tmp); xca = tgt_a + qpos (into xq buffer)
    hipLaunchKernelGGL(ln_resid, dim3(3600), b256, 0, stream,
                       tgt, tmp, ln2g, ln2b, tgt_a, qpos, xq);
    // 7. value = memory @ vproj^T + b
    hipLaunchKernelGGL(gemm_nt, dim3(704, 4), b256, 0, stream,
                       mem, vp_w, vp_b, value, VROWS, 256, 256, 256, 0);
    // 8. sampling offsets
    hipLaunchKernelGGL(gemm_nt, dim3(57, 4), b256, 0, stream,
                       xq, off_w, off_b, off_raw, NROW, 256, 256, 256, 0);
    // 9. attention-weight logits
    hipLaunchKernelGGL(gemm_nt, dim3(57, 2), b256, 0, stream,
                       xq, aw_w, aw_b, aw_raw, NROW, 128, 256, 128, 0);
    // 10. deformable sampling -> att buffer (reused)
    hipLaunchKernelGGL(msdeform_kernel, dim3(3600), b256, 0, stream,
                       off_raw, aw_raw, refp, value, att);
    // 11. oproj
    hipLaunchKernelGGL(gemm_nt, dim3(57, 4), b256, 0, stream,
                       att, op_w, op_b, tmp, NROW, 256, 256, 256, 0);
    // 12. tgt_b = LN1(tgt_a + tmp)
    hipLaunchKernelGGL(ln_resid, dim3(3600), b256, 0, stream,
                       tgt_a, tmp, ln1g, ln1b, tgt_b, (const float*)nullptr, (float*)nullptr);
    // 13. hidden = relu(tgt_b @ lin1^T + b)
    hipLaunchKernelGGL(gemm_nt, dim3(57, 16), b256, 0, stream,
                       tgt_b, l1w, l1b, hidden, NROW, 1024, 256, 1024, 1);
    // 14. tmp = hidden @ lin2^T + b
    hipLaunchKernelGGL(gemm_nt, dim3(57, 4), b256, 0, stream,
                       hidden, l2w, l2b, tmp, NROW, 256, 1024, 256, 0);
    // 15. out = LN3(tgt_b + tmp)
    hipLaunchKernelGGL(ln_resid, dim3(3600), b256, 0, stream,
                       tgt_b, tmp, ln3g, ln3b, out, (const float*)nullptr, (float*)nullptr);
}

// Round 2
// 417.186 us; speedup vs baseline: 1.4095x; 1.4095x over previous
//
#include <hip/hip_runtime.h>
#include <math.h>

#define D_MODEL 256
#define NHEAD   8
#define NLVL    4
#define NPTS    4
#define DHEAD   32
#define DFFN    1024
#define NQ      900
#define BSZ     4
#define NROW    (NQ * BSZ)      // 3600
#define S_TOT   11253
#define VROWS   (S_TOT * BSZ)   // 45012

typedef __attribute__((ext_vector_type(8))) short short8;
typedef __attribute__((ext_vector_type(4))) float f32x4;

static __device__ __forceinline__ unsigned f2bf1(float f) {
    unsigned u = __float_as_uint(f);
    return (u + 0x7FFFu + ((u >> 16) & 1u)) >> 16;
}
static __device__ __forceinline__ unsigned pack2bf(float x, float y) {
    return f2bf1(x) | (f2bf1(y) << 16);
}

// ---------------------------------------------------------------------------
// bf16 MFMA GEMM:  C[m,n] = sum_k A[m,k]*W[n,k] + bias[n]   (fp32 in/out)
// A: M x K row-major, W: N x K row-major. N % 64 == 0, K % 64 == 0.
// Block tile 64x64, BK=64, 4 waves each computing 16 rows x 64 cols via
// four 16x16x32 MFMAs per K-half.
// ---------------------------------------------------------------------------
#define GPAD 72   // LDS row stride in bf16 elements (64 + 8): even bank spread

__global__ __launch_bounds__(256) void gemm_bf16(
    const float* __restrict__ A, const float* __restrict__ W,
    const float* __restrict__ bias, float* __restrict__ C,
    int M, int N, int K, int ldc, int relu)
{
    __shared__ unsigned short As[64 * GPAD];
    __shared__ unsigned short Ws[64 * GPAD];

    const int t  = threadIdx.x;
    const int m0 = blockIdx.x * 64;
    const int n0 = blockIdx.y * 64;

    const int trow = t >> 2;          // 0..63 staging row
    const int tk   = (t & 3) << 4;    // 0,16,32,48 staging k-offset

    const int wv   = t >> 6;          // wave 0..3
    const int ln   = t & 63;
    const int mfr  = ln & 15;         // fragment row/col index
    const int quad = ln >> 4;         // 0..3

    f32x4 acc[4] = {{0.f,0.f,0.f,0.f},{0.f,0.f,0.f,0.f},
                    {0.f,0.f,0.f,0.f},{0.f,0.f,0.f,0.f}};

    for (int k0 = 0; k0 < K; k0 += 64) {
        // ---- stage A (with M guard) ----
        {
            int m = m0 + trow;
            float4 a0, a1, a2, a3;
            if (m < M) {
                const float* ap = A + (size_t)m * K + k0 + tk;
                a0 = *(const float4*)(ap + 0);
                a1 = *(const float4*)(ap + 4);
                a2 = *(const float4*)(ap + 8);
                a3 = *(const float4*)(ap + 12);
            } else {
                a0 = a1 = a2 = a3 = make_float4(0.f, 0.f, 0.f, 0.f);
            }
            uint4 u0, u1;
            u0.x = pack2bf(a0.x, a0.y); u0.y = pack2bf(a0.z, a0.w);
            u0.z = pack2bf(a1.x, a1.y); u0.w = pack2bf(a1.z, a1.w);
            u1.x = pack2bf(a2.x, a2.y); u1.y = pack2bf(a2.z, a2.w);
            u1.z = pack2bf(a3.x, a3.y); u1.w = pack2bf(a3.z, a3.w);
            *(uint4*)&As[trow * GPAD + tk + 0] = u0;
            *(uint4*)&As[trow * GPAD + tk + 8] = u1;
        }
        // ---- stage W (always in range) ----
        {
            int n = n0 + trow;
            const float* wp = W + (size_t)n * K + k0 + tk;
            float4 a0 = *(const float4*)(wp + 0);
            float4 a1 = *(const float4*)(wp + 4);
            float4 a2 = *(const float4*)(wp + 8);
            float4 a3 = *(const float4*)(wp + 12);
            uint4 u0, u1;
            u0.x = pack2bf(a0.x, a0.y); u0.y = pack2bf(a0.z, a0.w);
            u0.z = pack2bf(a1.x, a1.y); u0.w = pack2bf(a1.z, a1.w);
            u1.x = pack2bf(a2.x, a2.y); u1.y = pack2bf(a2.z, a2.w);
            u1.z = pack2bf(a3.x, a3.y); u1.w = pack2bf(a3.z, a3.w);
            *(uint4*)&Ws[trow * GPAD + tk + 0] = u0;
            *(uint4*)&Ws[trow * GPAD + tk + 8] = u1;
        }
        __syncthreads();

#pragma unroll
        for (int kh = 0; kh < 2; ++kh) {
            short8 af = *(const short8*)&As[(wv * 16 + mfr) * GPAD + kh * 32 + quad * 8];
#pragma unroll
            for (int cb = 0; cb < 4; ++cb) {
                short8 bf = *(const short8*)&Ws[(cb * 16 + mfr) * GPAD + kh * 32 + quad * 8];
                acc[cb] = __builtin_amdgcn_mfma_f32_16x16x32_bf16(af, bf, acc[cb], 0, 0, 0);
            }
        }
        __syncthreads();
    }

    // ---- epilogue: C/D layout col=lane&15, row=quad*4+reg ----
#pragma unroll
    for (int cb = 0; cb < 4; ++cb) {
        int col = n0 + cb * 16 + mfr;
        float bv = bias[col];
#pragma unroll
        for (int i = 0; i < 4; ++i) {
            int m = m0 + wv * 16 + quad * 4 + i;
            if (m < M) {
                float o = acc[cb][i] + bv;
                if (relu) o = fmaxf(o, 0.f);
                C[(size_t)m * ldc + col] = o;
            }
        }
    }
}

// ---------------------------------------------------------------------------
// Elementwise add (float4): c = a + b
// ---------------------------------------------------------------------------
__global__ void add_vec(const float* __restrict__ a, const float* __restrict__ b,
                        float* __restrict__ c, int n4)
{
    int i = blockIdx.x * blockDim.x + threadIdx.x;
    if (i < n4) {
        float4 x = ((const float4*)a)[i];
        float4 y = ((const float4*)b)[i];
        float4 z;
        z.x = x.x + y.x; z.y = x.y + y.y; z.z = x.z + y.z; z.w = x.w + y.w;
        ((float4*)c)[i] = z;
    }
}

// ---------------------------------------------------------------------------
// Self-attention.  qkv: (3600, 768) rows=(q*4+b), cols=[q(256)|k(256)|v(256)].
// One block per (q-tile of 32, b, h).  2-pass online softmax, K/V staged LDS.
// out: (3600, 256) rows=(q*4+b), cols=h*32+d
// ---------------------------------------------------------------------------
#define KT 64
#define KSTRIDE 36   // LDS row stride for K/V tiles (16B aligned, bank-spread)

__global__ __launch_bounds__(256) void sa_kernel(
    const float* __restrict__ qkv, float* __restrict__ attn_out)
{
    const int t  = threadIdx.x;
    const int q0 = blockIdx.x * 32;
    const int bh = blockIdx.y;
    const int b  = bh & 3;
    const int h  = bh >> 2;
    const int ql = t & 31;
    const int g  = t >> 5;        // 0..7
    const int q  = q0 + ql;
    const bool qvalid = (q < NQ);

    __shared__ float smem[9216];          // Ks[64][36] | Vs[64][36]; overlay opart[8][32][36]
    float* Ks = smem;
    float* Vs = smem + KT * KSTRIDE;      // +2304
    __shared__ float mred[8][32];
    __shared__ float lred[8][32];
    __shared__ float msh[32];
    __shared__ float lish[32];

    // load Q row into registers
    float qr[32];
    const float* qbase = qkv + ((size_t)q * 4 + b) * 768 + h * 32;
#pragma unroll
    for (int d4 = 0; d4 < 32; d4 += 4) {
        float4 v = qvalid ? *(const float4*)(qbase + d4) : make_float4(0.f, 0.f, 0.f, 0.f);
        qr[d4 + 0] = v.x; qr[d4 + 1] = v.y; qr[d4 + 2] = v.z; qr[d4 + 3] = v.w;
    }
    const float scale = 0.17677669529663687f;  // 1/sqrt(32)

    // ---- pass A: per-thread online (max, sumexp) over strided keys ----
    float m_t = -1e30f, l_t = 0.f;
    for (int k0 = 0; k0 < NQ; k0 += KT) {
        int kmax = NQ - k0; if (kmax > KT) kmax = KT;
        for (int i = t; i < 512; i += 256) {        // 512 float4 = 64x32 tile
            int krow = i >> 3, c4 = (i & 7) << 2;
            float4 kv = make_float4(0.f, 0.f, 0.f, 0.f);
            if (krow < kmax)
                kv = *(const float4*)(qkv + ((size_t)(k0 + krow) * 4 + b) * 768 + 256 + h * 32 + c4);
            *(float4*)&Ks[krow * KSTRIDE + c4] = kv;
        }
        __syncthreads();
        for (int kk = g; kk < kmax; kk += 8) {
            float s = 0.f;
#pragma unroll
            for (int d4 = 0; d4 < 32; d4 += 4) {
                float4 kv = *(const float4*)&Ks[kk * KSTRIDE + d4];
                s = fmaf(qr[d4 + 0], kv.x, s);
                s = fmaf(qr[d4 + 1], kv.y, s);
                s = fmaf(qr[d4 + 2], kv.z, s);
                s = fmaf(qr[d4 + 3], kv.w, s);
            }
            s *= scale;
            float mn = fmaxf(m_t, s);
            l_t = l_t * __expf(m_t - mn) + __expf(s - mn);
            m_t = mn;
        }
        __syncthreads();
    }
    mred[g][ql] = m_t;
    lred[g][ql] = l_t;
    __syncthreads();
    if (t < 32) {
        float m = mred[0][t];
#pragma unroll
        for (int i = 1; i < 8; ++i) m = fmaxf(m, mred[i][t]);
        float l = 0.f;
#pragma unroll
        for (int i = 0; i < 8; ++i) l += lred[i][t] * __expf(mred[i][t] - m);
        msh[t] = m;
        lish[t] = 1.f / l;
    }
    __syncthreads();
    const float mq  = msh[ql];
    const float liq = lish[ql];

    // ---- pass B: recompute scores, accumulate P*V ----
    float acc[32] = {};
    for (int k0 = 0; k0 < NQ; k0 += KT) {
        int kmax = NQ - k0; if (kmax > KT) kmax = KT;
        for (int i = t; i < 512; i += 256) {
            int krow = i >> 3, c4 = (i & 7) << 2;
            float4 kv = make_float4(0.f, 0.f, 0.f, 0.f);
            float4 vv = make_float4(0.f, 0.f, 0.f, 0.f);
            if (krow < kmax) {
                const float* base = qkv + ((size_t)(k0 + krow) * 4 + b) * 768 + 256 + h * 32 + c4;
                kv = *(const float4*)base;
                vv = *(const float4*)(base + 256);
            }
            *(float4*)&Ks[krow * KSTRIDE + c4] = kv;
            *(float4*)&Vs[krow * KSTRIDE + c4] = vv;
        }
        __syncthreads();
        for (int kk = g; kk < kmax; kk += 8) {
            float s = 0.f;
#pragma unroll
            for (int d4 = 0; d4 < 32; d4 += 4) {
                float4 kv = *(const float4*)&Ks[kk * KSTRIDE + d4];
                s = fmaf(qr[d4 + 0], kv.x, s);
                s = fmaf(qr[d4 + 1], kv.y, s);
                s = fmaf(qr[d4 + 2], kv.z, s);
                s = fmaf(qr[d4 + 3], kv.w, s);
            }
            s *= scale;
            float p = __expf(s - mq) * liq;
#pragma unroll
            for (int d4 = 0; d4 < 32; d4 += 4) {
                float4 vv = *(const float4*)&Vs[kk * KSTRIDE + d4];
                acc[d4 + 0] = fmaf(p, vv.x, acc[d4 + 0]);
                acc[d4 + 1] = fmaf(p, vv.y, acc[d4 + 1]);
                acc[d4 + 2] = fmaf(p, vv.z, acc[d4 + 2]);
                acc[d4 + 3] = fmaf(p, vv.w, acc[d4 + 3]);
            }
        }
        __syncthreads();
    }

    // reduce the 8 strided partials (overlay the K/V staging memory)
    float* opart = smem;   // [8][32][36]
#pragma unroll
    for (int d4 = 0; d4 < 32; d4 += 4)
        *(float4*)&opart[g * 1152 + ql * 36 + d4] =
            make_float4(acc[d4], acc[d4 + 1], acc[d4 + 2], acc[d4 + 3]);
    __syncthreads();
#pragma unroll
    for (int j = 0; j < 4; ++j) {
        int idx = t + j * 256;
        int qq = idx >> 5, dd = idx & 31;
        float s = 0.f;
#pragma unroll
        for (int gg = 0; gg < 8; ++gg) s += opart[gg * 1152 + qq * 36 + dd];
        if (q0 + qq < NQ)
            attn_out[((size_t)(q0 + qq) * 4 + b) * 256 + h * 32 + dd] = s;
    }
}

// ---------------------------------------------------------------------------
// Residual + LayerNorm (optionally also emits y + pos into out2).
// ---------------------------------------------------------------------------
__global__ __launch_bounds__(256) void ln_resid(
    const float* __restrict__ xa, const float* __restrict__ xb,
    const float* __restrict__ gam, const float* __restrict__ bet,
    float* __restrict__ out, const float* __restrict__ pos, float* __restrict__ out2)
{
    const int row = blockIdx.x;
    const int t = threadIdx.x;
    float x = xa[(size_t)row * D_MODEL + t] + xb[(size_t)row * D_MODEL + t];
    float s = x, s2 = x * x;
#pragma unroll
    for (int off = 32; off > 0; off >>= 1) {
        s  += __shfl_down(s, off, 64);
        s2 += __shfl_down(s2, off, 64);
    }
    __shared__ float rs[4], rs2[4];
    __shared__ float mean_s, rstd_s;
    int wid = t >> 6, lane = t & 63;
    if (lane == 0) { rs[wid] = s; rs2[wid] = s2; }
    __syncthreads();
    if (t == 0) {
        float S = rs[0] + rs[1] + rs[2] + rs[3];
        float S2 = rs2[0] + rs2[1] + rs2[2] + rs2[3];
        float mean = S * (1.f / 256.f);
        float var = S2 * (1.f / 256.f) - mean * mean;
        mean_s = mean;
        rstd_s = rsqrtf(var + 1e-5f);
    }
    __syncthreads();
    float y = (x - mean_s) * rstd_s * gam[t] + bet[t];
    out[(size_t)row * D_MODEL + t] = y;
    if (out2) out2[(size_t)row * D_MODEL + t] = y + pos[(size_t)row * D_MODEL + t];
}

// ---------------------------------------------------------------------------
// Multi-scale deformable sampling.
// ---------------------------------------------------------------------------
__global__ __launch_bounds__(256) void msdeform_kernel(
    const float* __restrict__ off_raw, const float* __restrict__ aw_raw,
    const float* __restrict__ refp, const float* __restrict__ value,
    float* __restrict__ out)
{
    const int row = blockIdx.x;   // q*4+b
    const int b = row & 3;
    const int t = threadIdx.x;

    __shared__ float aw_s[8][17];
    __shared__ float px_s[8][16];
    __shared__ float py_s[8][16];

    const int Hs[4]  = {92, 46, 23, 12};
    const int Wd[4]  = {92, 46, 23, 12};
    const int S0_[4] = {0, 8464, 10580, 11109};

    if (t < 128) {
        int hh = t >> 4, lp = t & 15, l = lp >> 2;
        float ox = off_raw[(size_t)row * 256 + hh * 32 + lp * 2 + 0];
        float oy = off_raw[(size_t)row * 256 + hh * 32 + lp * 2 + 1];
        float rx = refp[((size_t)row * 4 + l) * 2 + 0];
        float ry = refp[((size_t)row * 4 + l) * 2 + 1];
        px_s[hh][lp] = rx * (float)Wd[l] + ox - 0.5f;
        py_s[hh][lp] = ry * (float)Hs[l] + oy - 0.5f;
    }
    if (t < 8) {
        int hh = t;
        float v[16];
        float m = -1e30f;
#pragma unroll
        for (int j = 0; j < 16; ++j) {
            v[j] = aw_raw[(size_t)row * 128 + hh * 16 + j];
            m = fmaxf(m, v[j]);
        }
        float ssum = 0.f;
#pragma unroll
        for (int j = 0; j < 16; ++j) { v[j] = __expf(v[j] - m); ssum += v[j]; }
        float inv = 1.f / ssum;
#pragma unroll
        for (int j = 0; j < 16; ++j) aw_s[hh][j] = v[j] * inv;
    }
    __syncthreads();

    const int h = t >> 5, d = t & 31;
    const float* vb = value + (size_t)b * 256 + h * 32 + d;
    float acc = 0.f;
#pragma unroll
    for (int l = 0; l < 4; ++l) {
        const int H = Hs[l], W = Wd[l], base = S0_[l];
#pragma unroll
        for (int p = 0; p < 4; ++p) {
            const int lp = l * 4 + p;
            float px = px_s[h][lp], py = py_s[h][lp];
            float x0f = floorf(px), y0f = floorf(py);
            int x0 = (int)x0f, y0 = (int)y0f;
            float wx = px - x0f, wy = py - y0f;
            float sv = 0.f;
#pragma unroll
            for (int dy = 0; dy < 2; ++dy) {
#pragma unroll
                for (int dx = 0; dx < 2; ++dx) {
                    int xi = x0 + dx, yi = y0 + dy;
                    float flag = (xi >= 0 && xi < W && yi >= 0 && yi < H) ? 1.f : 0.f;
                    int xc = xi < 0 ? 0 : (xi >= W ? W - 1 : xi);
                    int yc = yi < 0 ? 0 : (yi >= H ? H - 1 : yi);
                    float wgt = (dx ? wx : 1.f - wx) * (dy ? wy : 1.f - wy);
                    float gv = vb[(size_t)(base + yc * W + xc) * 1024];
                    sv = fmaf(wgt * flag, gv, sv);
                }
            }
            acc = fmaf(aw_s[h][lp], sv, acc);
        }
    }
    out[(size_t)row * 256 + h * 32 + d] = acc;
}

// ---------------------------------------------------------------------------
extern "C" void kernel_launch(void* const* d_in, const int* in_sizes, int n_in,
                              void* d_out, int out_size, void* d_ws, size_t ws_size,
                              hipStream_t stream)
{
    const float* tgt    = (const float*)d_in[0];
    const float* qpos   = (const float*)d_in[1];
    const float* refp   = (const float*)d_in[2];
    const float* mem    = (const float*)d_in[3];
    const float* in_w   = (const float*)d_in[6];
    const float* in_b   = (const float*)d_in[7];
    const float* outp_w = (const float*)d_in[8];
    const float* outp_b = (const float*)d_in[9];
    const float* off_w  = (const float*)d_in[10];
    const float* off_b  = (const float*)d_in[11];
    const float* aw_w   = (const float*)d_in[12];
    const float* aw_b   = (const float*)d_in[13];
    const float* vp_w   = (const float*)d_in[14];
    const float* vp_b   = (const float*)d_in[15];
    const float* op_w   = (const float*)d_in[16];
    const float* op_b   = (const float*)d_in[17];
    const float* ln1g   = (const float*)d_in[18];
    const float* ln1b   = (const float*)d_in[19];
    const float* ln2g   = (const float*)d_in[20];
    const float* ln2b   = (const float*)d_in[21];
    const float* ln3g   = (const float*)d_in[22];
    const float* ln3b   = (const float*)d_in[23];
    const float* l1w    = (const float*)d_in[24];
    const float* l1b    = (const float*)d_in[25];
    const float* l2w    = (const float*)d_in[26];
    const float* l2b    = (const float*)d_in[27];
    float* out = (float*)d_out;
    float* ws  = (float*)d_ws;

    float* qkv     = ws;                 // 3600*768
    float* off_raw = ws;                 // reuse of qkv region (after SA done)
    float* aw_raw  = ws + 921600;
    float* xq      = ws + 2764800;
    float* att     = ws + 3686400;
    float* tmp     = ws + 4608000;
    float* tgt_a   = ws + 5529600;
    float* tgt_b   = ws + 6451200;
    float* value   = ws + 7372800;       // 45012*256
    float* hidden  = value;              // reuse after sampling

    dim3 b256(256);

    // 1. xq = tgt + qpos
    hipLaunchKernelGGL(add_vec, dim3(900), b256, 0, stream, tgt, qpos, xq, 230400);
    // 2. qkv[:, 0:512] = xq @ [wq;wk]^T + b
    hipLaunchKernelGGL(gemm_bf16, dim3(57, 8), b256, 0, stream,
                       xq, in_w, in_b, qkv, NROW, 512, 256, 768, 0);
    // 3. qkv[:, 512:768] = tgt @ wv^T + bv
    hipLaunchKernelGGL(gemm_bf16, dim3(57, 4), b256, 0, stream,
                       tgt, in_w + 512 * 256, in_b + 512, qkv + 512, NROW, 256, 256, 768, 0);
    // 4. self-attention
    hipLaunchKernelGGL(sa_kernel, dim3(29, 32), b256, 0, stream, qkv, att);
    // 5. attention out-proj
    hipLaunchKernelGGL(gemm_bf16, dim3(57, 4), b256, 0, stream,
                       att, outp_w, outp_b, tmp, NROW, 256, 256, 256, 0);
    // 6. tgt_a = LN2(tgt + tmp); xca = tgt_a + qpos (into xq buffer)
    hipLaunchKernelGGL(ln_resid, dim3(3600), b256, 0, stream,
                       tgt, tmp, ln2g, ln2b, tgt_a, qpos, xq);
    // 7. value = memory @ vproj^T + b
    hipLaunchKernelGGL(gemm_bf16, dim3(704, 4), b256, 0, stream,
                       mem, vp_w, vp_b, value, VROWS, 256, 256, 256, 0);
    // 8. sampling offsets
    hipLaunchKernelGGL(gemm_bf16, dim3(57, 4), b256, 0, stream,
                       xq, off_w, off_b, off_raw, NROW, 256, 256, 256, 0);
    // 9. attention-weight logits
    hipLaunchKernelGGL(gemm_bf16, dim3(57, 2), b256, 0, stream,
                       xq, aw_w, aw_b, aw_raw, NROW, 128, 256, 128, 0);
    // 10. deformable sampling -> att buffer (reused)
    hipLaunchKernelGGL(msdeform_kernel, dim3(3600), b256, 0, stream,
                       off_raw, aw_raw, refp, value, att);
    // 11. oproj
    hipLaunchKernelGGL(gemm_bf16, dim3(57, 4), b256, 0, stream,
                       att, op_w, op_b, tmp, NROW, 256, 256, 256, 0);
    // 12. tgt_b = LN1(tgt_a + tmp)
    hipLaunchKernelGGL(ln_resid, dim3(3600), b256, 0, stream,
                       tgt_a, tmp, ln1g, ln1b, tgt_b, (const float*)nullptr, (float*)nullptr);
    // 13. hidden = relu(tgt_b @ lin1^T + b)
    hipLaunchKernelGGL(gemm_bf16, dim3(57, 16), b256, 0, stream,
                       tgt_b, l1w, l1b, hidden, NROW, 1024, 256, 1024, 1);
    // 14. tmp = hidden @ lin2^T + b
    hipLaunchKernelGGL(gemm_bf16, dim3(57, 4), b256, 0, stream,
                       hidden, l2w, l2b, tmp, NROW, 256, 1024, 256, 0);
    // 15. out = LN3(tgt_b + tmp)
    hipLaunchKernelGGL(ln_resid, dim3(3600), b256, 0, stream,
                       tgt_b, tmp, ln3g, ln3b, out, (const float*)nullptr, (float*)nullptr);
}

// Round 3
// 323.378 us; speedup vs baseline: 1.8184x; 1.2901x over previous
//
#include <hip/hip_runtime.h>
#include <math.h>

#define D_MODEL 256
#define NHEAD   8
#define NLVL    4
#define NPTS    4
#define DHEAD   32
#define DFFN    1024
#define NQ      900
#define BSZ     4
#define NROW    (NQ * BSZ)      // 3600
#define S_TOT   11253
#define VROWS   (S_TOT * BSZ)   // 45012

typedef __attribute__((ext_vector_type(8))) short short8;
typedef __attribute__((ext_vector_type(4))) float f32x4;

static __device__ __forceinline__ unsigned f2bf1(float f) {
    unsigned u = __float_as_uint(f);
    return (u + 0x7FFFu + ((u >> 16) & 1u)) >> 16;
}
static __device__ __forceinline__ unsigned pack2bf(float x, float y) {
    return f2bf1(x) | (f2bf1(y) << 16);
}

// ---------------------------------------------------------------------------
// bf16 MFMA GEMM:  C[m,n] = sum_k A[m,k]*W[n,k] + bias[n]   (fp32 in/out)
// ---------------------------------------------------------------------------
#define GPAD 72

__global__ __launch_bounds__(256) void gemm_bf16(
    const float* __restrict__ A, const float* __restrict__ W,
    const float* __restrict__ bias, float* __restrict__ C,
    int M, int N, int K, int ldc, int relu)
{
    __shared__ unsigned short As[64 * GPAD];
    __shared__ unsigned short Ws[64 * GPAD];

    const int t  = threadIdx.x;
    const int m0 = blockIdx.x * 64;
    const int n0 = blockIdx.y * 64;

    const int trow = t >> 2;
    const int tk   = (t & 3) << 4;

    const int wv   = t >> 6;
    const int ln   = t & 63;
    const int mfr  = ln & 15;
    const int quad = ln >> 4;

    f32x4 acc[4] = {{0.f,0.f,0.f,0.f},{0.f,0.f,0.f,0.f},
                    {0.f,0.f,0.f,0.f},{0.f,0.f,0.f,0.f}};

    for (int k0 = 0; k0 < K; k0 += 64) {
        {
            int m = m0 + trow;
            float4 a0, a1, a2, a3;
            if (m < M) {
                const float* ap = A + (size_t)m * K + k0 + tk;
                a0 = *(const float4*)(ap + 0);
                a1 = *(const float4*)(ap + 4);
                a2 = *(const float4*)(ap + 8);
                a3 = *(const float4*)(ap + 12);
            } else {
                a0 = a1 = a2 = a3 = make_float4(0.f, 0.f, 0.f, 0.f);
            }
            uint4 u0, u1;
            u0.x = pack2bf(a0.x, a0.y); u0.y = pack2bf(a0.z, a0.w);
            u0.z = pack2bf(a1.x, a1.y); u0.w = pack2bf(a1.z, a1.w);
            u1.x = pack2bf(a2.x, a2.y); u1.y = pack2bf(a2.z, a2.w);
            u1.z = pack2bf(a3.x, a3.y); u1.w = pack2bf(a3.z, a3.w);
            *(uint4*)&As[trow * GPAD + tk + 0] = u0;
            *(uint4*)&As[trow * GPAD + tk + 8] = u1;
        }
        {
            int n = n0 + trow;
            const float* wp = W + (size_t)n * K + k0 + tk;
            float4 a0 = *(const float4*)(wp + 0);
            float4 a1 = *(const float4*)(wp + 4);
            float4 a2 = *(const float4*)(wp + 8);
            float4 a3 = *(const float4*)(wp + 12);
            uint4 u0, u1;
            u0.x = pack2bf(a0.x, a0.y); u0.y = pack2bf(a0.z, a0.w);
            u0.z = pack2bf(a1.x, a1.y); u0.w = pack2bf(a1.z, a1.w);
            u1.x = pack2bf(a2.x, a2.y); u1.y = pack2bf(a2.z, a2.w);
            u1.z = pack2bf(a3.x, a3.y); u1.w = pack2bf(a3.z, a3.w);
            *(uint4*)&Ws[trow * GPAD + tk + 0] = u0;
            *(uint4*)&Ws[trow * GPAD + tk + 8] = u1;
        }
        __syncthreads();

#pragma unroll
        for (int kh = 0; kh < 2; ++kh) {
            short8 af = *(const short8*)&As[(wv * 16 + mfr) * GPAD + kh * 32 + quad * 8];
#pragma unroll
            for (int cb = 0; cb < 4; ++cb) {
                short8 bf = *(const short8*)&Ws[(cb * 16 + mfr) * GPAD + kh * 32 + quad * 8];
                acc[cb] = __builtin_amdgcn_mfma_f32_16x16x32_bf16(af, bf, acc[cb], 0, 0, 0);
            }
        }
        __syncthreads();
    }

#pragma unroll
    for (int cb = 0; cb < 4; ++cb) {
        int col = n0 + cb * 16 + mfr;
        float bv = bias[col];
#pragma unroll
        for (int i = 0; i < 4; ++i) {
            int m = m0 + wv * 16 + quad * 4 + i;
            if (m < M) {
                float o = acc[cb][i] + bv;
                if (relu) o = fmaxf(o, 0.f);
                C[(size_t)m * ldc + col] = o;
            }
        }
    }
}

// ---------------------------------------------------------------------------
// Elementwise add
// ---------------------------------------------------------------------------
__global__ void add_vec(const float* __restrict__ a, const float* __restrict__ b,
                        float* __restrict__ c, int n4)
{
    int i = blockIdx.x * blockDim.x + threadIdx.x;
    if (i < n4) {
        float4 x = ((const float4*)a)[i];
        float4 y = ((const float4*)b)[i];
        float4 z;
        z.x = x.x + y.x; z.y = x.y + y.y; z.z = x.z + y.z; z.w = x.w + y.w;
        ((float4*)c)[i] = z;
    }
}

// ---------------------------------------------------------------------------
// MFMA flash self-attention.
// qkv: (3600, 768) rows=(q*4+b), cols=[q|k|v].  out: (3600, 256) col=h*32+d.
// Grid (ceil(900/64)=15, 32=b*h). Block 256 = 4 waves x 16 queries each.
// S^T = K·Q^T so lane&15 = query (cheap softmax + P pack); PV via Vt in LDS.
// ---------------------------------------------------------------------------
__global__ __launch_bounds__(256) void sa_flash(
    const float* __restrict__ qkv, float* __restrict__ attn_out)
{
    __shared__ unsigned short Ks[2 * 2080];   // 2 bufs x 4 d-planes x (64*8+8)
    __shared__ unsigned short Vt[2 * 2304];   // 2 bufs x 32 d-rows x 72
    __shared__ unsigned short Ps[4 * 1152];   // 4 waves x 16 q-rows x 72

    const int t    = threadIdx.x;
    const int q0   = blockIdx.x * 64;
    const int b    = blockIdx.y & 3;
    const int h    = blockIdx.y >> 2;
    const int wv   = t >> 6;
    const int ln   = t & 63;
    const int L    = ln & 15;
    const int quad = ln >> 4;

    const float scale = 0.17677669529663687f;  // 1/sqrt(32)

    // ---- Q fragment (pre-scaled): A/B-frag [n=query=L][k=d=quad*8+j] ----
    union { uint4 u; short8 s; } qu;
    qu.u = make_uint4(0u, 0u, 0u, 0u);
    {
        int q = q0 + wv * 16 + L;
        if (q < NQ) {
            const float* qp = qkv + ((size_t)q * 4 + b) * 768 + h * 32 + quad * 8;
            float4 f0 = *(const float4*)qp;
            float4 f1 = *(const float4*)(qp + 4);
            qu.u.x = pack2bf(f0.x * scale, f0.y * scale);
            qu.u.y = pack2bf(f0.z * scale, f0.w * scale);
            qu.u.z = pack2bf(f1.x * scale, f1.y * scale);
            qu.u.w = pack2bf(f1.z * scale, f1.w * scale);
        }
    }
    const short8 qf = qu.s;

    float mrun = -1e30f, lrun = 0.f;
    f32x4 oacc[2] = {{0.f,0.f,0.f,0.f},{0.f,0.f,0.f,0.f}};

    const int skey = t >> 2;       // staging key 0..63
    const int sdg  = t & 3;        // staging d-group 0..3

    int it = 0;
    for (int k0 = 0; k0 < NQ; k0 += 64, it ^= 1) {
        // ---- stage K (frag layout) and V (transposed) into buffer `it` ----
        {
            int kg = k0 + skey;
            float4 f0, f1, g0, g1;
            if (kg < NQ) {
                const float* kp = qkv + ((size_t)kg * 4 + b) * 768 + 256 + h * 32 + sdg * 8;
                f0 = *(const float4*)kp;
                f1 = *(const float4*)(kp + 4);
                g0 = *(const float4*)(kp + 256);
                g1 = *(const float4*)(kp + 260);
            } else {
                f0 = f1 = g0 = g1 = make_float4(0.f, 0.f, 0.f, 0.f);
            }
            uint4 ku;
            ku.x = pack2bf(f0.x, f0.y); ku.y = pack2bf(f0.z, f0.w);
            ku.z = pack2bf(f1.x, f1.y); ku.w = pack2bf(f1.z, f1.w);
            *(uint4*)&Ks[it * 2080 + sdg * 520 + skey * 8] = ku;
            unsigned short* vp = &Vt[it * 2304 + sdg * 8 * 72 + skey];
            vp[0 * 72] = (unsigned short)f2bf1(g0.x);
            vp[1 * 72] = (unsigned short)f2bf1(g0.y);
            vp[2 * 72] = (unsigned short)f2bf1(g0.z);
            vp[3 * 72] = (unsigned short)f2bf1(g0.w);
            vp[4 * 72] = (unsigned short)f2bf1(g1.x);
            vp[5 * 72] = (unsigned short)f2bf1(g1.y);
            vp[6 * 72] = (unsigned short)f2bf1(g1.z);
            vp[7 * 72] = (unsigned short)f2bf1(g1.w);
        }
        __syncthreads();

        // ---- S^T = K·Q^T : D[m=key][n=query], 4 key-blocks ----
        f32x4 sacc[4] = {{0.f,0.f,0.f,0.f},{0.f,0.f,0.f,0.f},
                         {0.f,0.f,0.f,0.f},{0.f,0.f,0.f,0.f}};
#pragma unroll
        for (int cb = 0; cb < 4; ++cb) {
            short8 kf = *(const short8*)&Ks[it * 2080 + quad * 520 + (cb * 16 + L) * 8];
            sacc[cb] = __builtin_amdgcn_mfma_f32_16x16x32_bf16(kf, qf, sacc[cb], 0, 0, 0);
        }
        // mask tail keys
        if (k0 + 64 > NQ) {
#pragma unroll
            for (int cb = 0; cb < 4; ++cb)
#pragma unroll
                for (int i = 0; i < 4; ++i)
                    if (k0 + cb * 16 + quad * 4 + i >= NQ) sacc[cb][i] = -1e30f;
        }

        // ---- online softmax (per query = per lane L, dup across quads) ----
        float ml = -1e30f;
#pragma unroll
        for (int cb = 0; cb < 4; ++cb)
#pragma unroll
            for (int i = 0; i < 4; ++i) ml = fmaxf(ml, sacc[cb][i]);
        ml = fmaxf(ml, __shfl_xor(ml, 16, 64));
        ml = fmaxf(ml, __shfl_xor(ml, 32, 64));
        float mnew  = fmaxf(mrun, ml);
        float alpha = __expf(mrun - mnew);
        float p[16];
        float rs = 0.f;
#pragma unroll
        for (int cb = 0; cb < 4; ++cb)
#pragma unroll
            for (int i = 0; i < 4; ++i) {
                float e = __expf(sacc[cb][i] - mnew);
                p[cb * 4 + i] = e;
                rs += e;
            }
        rs += __shfl_xor(rs, 16, 64);
        rs += __shfl_xor(rs, 32, 64);
        lrun = lrun * alpha + rs;
        mrun = mnew;

        // ---- write P row (query L): lane's 4 regs = 4 consecutive keys ----
        {
            unsigned short* pw = &Ps[wv * 1152 + L * 72];
#pragma unroll
            for (int cb = 0; cb < 4; ++cb) {
                uint2 u;
                u.x = pack2bf(p[cb * 4 + 0], p[cb * 4 + 1]);
                u.y = pack2bf(p[cb * 4 + 2], p[cb * 4 + 3]);
                *(uint2*)&pw[cb * 16 + quad * 4] = u;
            }
        }
        // ---- rescale O (rows are query=quad*4+i -> fetch alpha via bperm) ----
#pragma unroll
        for (int i = 0; i < 4; ++i) {
            float ai = __shfl(alpha, quad * 4 + i, 64);
            oacc[0][i] *= ai;
            oacc[1][i] *= ai;
        }
        __syncthreads();

        // ---- PV: O[m=query][n=d] += P·V ----
#pragma unroll
        for (int ks = 0; ks < 2; ++ks) {
            short8 pf = *(const short8*)&Ps[wv * 1152 + L * 72 + ks * 32 + quad * 8];
#pragma unroll
            for (int db = 0; db < 2; ++db) {
                short8 vf = *(const short8*)&Vt[it * 2304 + (db * 16 + L) * 72 + ks * 32 + quad * 8];
                oacc[db] = __builtin_amdgcn_mfma_f32_16x16x32_bf16(pf, vf, oacc[db], 0, 0, 0);
            }
        }
    }

    // ---- epilogue ----
#pragma unroll
    for (int i = 0; i < 4; ++i) {
        float lq = __shfl(lrun, quad * 4 + i, 64);
        float li = 1.f / lq;
        int q = q0 + wv * 16 + quad * 4 + i;
        if (q < NQ) {
            float* op = attn_out + ((size_t)q * 4 + b) * 256 + h * 32 + L;
            op[0]  = oacc[0][i] * li;
            op[16] = oacc[1][i] * li;
        }
    }
}

// ---------------------------------------------------------------------------
// Residual + LayerNorm (optionally also emits y + pos into out2).
// ---------------------------------------------------------------------------
__global__ __launch_bounds__(256) void ln_resid(
    const float* __restrict__ xa, const float* __restrict__ xb,
    const float* __restrict__ gam, const float* __restrict__ bet,
    float* __restrict__ out, const float* __restrict__ pos, float* __restrict__ out2)
{
    const int row = blockIdx.x;
    const int t = threadIdx.x;
    float x = xa[(size_t)row * D_MODEL + t] + xb[(size_t)row * D_MODEL + t];
    float s = x, s2 = x * x;
#pragma unroll
    for (int off = 32; off > 0; off >>= 1) {
        s  += __shfl_down(s, off, 64);
        s2 += __shfl_down(s2, off, 64);
    }
    __shared__ float rs[4], rs2[4];
    __shared__ float mean_s, rstd_s;
    int wid = t >> 6, lane = t & 63;
    if (lane == 0) { rs[wid] = s; rs2[wid] = s2; }
    __syncthreads();
    if (t == 0) {
        float S = rs[0] + rs[1] + rs[2] + rs[3];
        float S2 = rs2[0] + rs2[1] + rs2[2] + rs2[3];
        float mean = S * (1.f / 256.f);
        float var = S2 * (1.f / 256.f) - mean * mean;
        mean_s = mean;
        rstd_s = rsqrtf(var + 1e-5f);
    }
    __syncthreads();
    float y = (x - mean_s) * rstd_s * gam[t] + bet[t];
    out[(size_t)row * D_MODEL + t] = y;
    if (out2) out2[(size_t)row * D_MODEL + t] = y + pos[(size_t)row * D_MODEL + t];
}

// ---------------------------------------------------------------------------
// Multi-scale deformable sampling.
// ---------------------------------------------------------------------------
__global__ __launch_bounds__(256) void msdeform_kernel(
    const float* __restrict__ off_raw, const float* __restrict__ aw_raw,
    const float* __restrict__ refp, const float* __restrict__ value,
    float* __restrict__ out)
{
    const int row = blockIdx.x;   // q*4+b
    const int b = row & 3;
    const int t = threadIdx.x;

    __shared__ float aw_s[8][17];
    __shared__ float px_s[8][16];
    __shared__ float py_s[8][16];

    const int Hs[4]  = {92, 46, 23, 12};
    const int Wd[4]  = {92, 46, 23, 12};
    const int S0_[4] = {0, 8464, 10580, 11109};

    if (t < 128) {
        int hh = t >> 4, lp = t & 15, l = lp >> 2;
        float ox = off_raw[(size_t)row * 256 + hh * 32 + lp * 2 + 0];
        float oy = off_raw[(size_t)row * 256 + hh * 32 + lp * 2 + 1];
        float rx = refp[((size_t)row * 4 + l) * 2 + 0];
        float ry = refp[((size_t)row * 4 + l) * 2 + 1];
        px_s[hh][lp] = rx * (float)Wd[l] + ox - 0.5f;
        py_s[hh][lp] = ry * (float)Hs[l] + oy - 0.5f;
    }
    if (t < 8) {
        int hh = t;
        float v[16];
        float m = -1e30f;
#pragma unroll
        for (int j = 0; j < 16; ++j) {
            v[j] = aw_raw[(size_t)row * 128 + hh * 16 + j];
            m = fmaxf(m, v[j]);
        }
        float ssum = 0.f;
#pragma unroll
        for (int j = 0; j < 16; ++j) { v[j] = __expf(v[j] - m); ssum += v[j]; }
        float inv = 1.f / ssum;
#pragma unroll
        for (int j = 0; j < 16; ++j) aw_s[hh][j] = v[j] * inv;
    }
    __syncthreads();

    const int h = t >> 5, d = t & 31;
    const float* vb = value + (size_t)b * 256 + h * 32 + d;
    float acc = 0.f;
#pragma unroll
    for (int l = 0; l < 4; ++l) {
        const int H = Hs[l], W = Wd[l], base = S0_[l];
#pragma unroll
        for (int p = 0; p < 4; ++p) {
            const int lp = l * 4 + p;
            float px = px_s[h][lp], py = py_s[h][lp];
            float x0f = floorf(px), y0f = floorf(py);
            int x0 = (int)x0f, y0 = (int)y0f;
            float wx = px - x0f, wy = py - y0f;
            float sv = 0.f;
#pragma unroll
            for (int dy = 0; dy < 2; ++dy) {
#pragma unroll
                for (int dx = 0; dx < 2; ++dx) {
                    int xi = x0 + dx, yi = y0 + dy;
                    float flag = (xi >= 0 && xi < W && yi >= 0 && yi < H) ? 1.f : 0.f;
                    int xc = xi < 0 ? 0 : (xi >= W ? W - 1 : xi);
                    int yc = yi < 0 ? 0 : (yi >= H ? H - 1 : yi);
                    float wgt = (dx ? wx : 1.f - wx) * (dy ? wy : 1.f - wy);
                    float gv = vb[(size_t)(base + yc * W + xc) * 1024];
                    sv = fmaf(wgt * flag, gv, sv);
                }
            }
            acc = fmaf(aw_s[h][lp], sv, acc);
        }
    }
    out[(size_t)row * 256 + h * 32 + d] = acc;
}

// ---------------------------------------------------------------------------
extern "C" void kernel_launch(void* const* d_in, const int* in_sizes, int n_in,
                              void* d_out, int out_size, void* d_ws, size_t ws_size,
                              hipStream_t stream)
{
    const float* tgt    = (const float*)d_in[0];
    const float* qpos   = (const float*)d_in[1];
    const float* refp   = (const float*)d_in[2];
    const float* mem    = (const float*)d_in[3];
    const float* in_w   = (const float*)d_in[6];
    const float* in_b   = (const float*)d_in[7];
    const float* outp_w = (const float*)d_in[8];
    const float* outp_b = (const float*)d_in[9];
    const float* off_w  = (const float*)d_in[10];
    const float* off_b  = (const float*)d_in[11];
    const float* aw_w   = (const float*)d_in[12];
    const float* aw_b   = (const float*)d_in[13];
    const float* vp_w   = (const float*)d_in[14];
    const float* vp_b   = (const float*)d_in[15];
    const float* op_w   = (const float*)d_in[16];
    const float* op_b   = (const float*)d_in[17];
    const float* ln1g   = (const float*)d_in[18];
    const float* ln1b   = (const float*)d_in[19];
    const float* ln2g   = (const float*)d_in[20];
    const float* ln2b   = (const float*)d_in[21];
    const float* ln3g   = (const float*)d_in[22];
    const float* ln3b   = (const float*)d_in[23];
    const float* l1w    = (const float*)d_in[24];
    const float* l1b    = (const float*)d_in[25];
    const float* l2w    = (const float*)d_in[26];
    const float* l2b    = (const float*)d_in[27];
    float* out = (float*)d_out;
    float* ws  = (float*)d_ws;

    float* qkv     = ws;                 // 3600*768
    float* off_raw = ws;                 // reuse of qkv region (after SA done)
    float* aw_raw  = ws + 921600;
    float* xq      = ws + 2764800;
    float* att     = ws + 3686400;
    float* tmp     = ws + 4608000;
    float* tgt_a   = ws + 5529600;
    float* tgt_b   = ws + 6451200;
    float* value   = ws + 7372800;       // 45012*256
    float* hidden  = value;              // reuse after sampling

    dim3 b256(256);

    // 1. xq = tgt + qpos
    hipLaunchKernelGGL(add_vec, dim3(900), b256, 0, stream, tgt, qpos, xq, 230400);
    // 2. qkv[:, 0:512] = xq @ [wq;wk]^T + b
    hipLaunchKernelGGL(gemm_bf16, dim3(57, 8), b256, 0, stream,
                       xq, in_w, in_b, qkv, NROW, 512, 256, 768, 0);
    // 3. qkv[:, 512:768] = tgt @ wv^T + bv
    hipLaunchKernelGGL(gemm_bf16, dim3(57, 4), b256, 0, stream,
                       tgt, in_w + 512 * 256, in_b + 512, qkv + 512, NROW, 256, 256, 768, 0);
    // 4. flash self-attention
    hipLaunchKernelGGL(sa_flash, dim3(15, 32), b256, 0, stream, qkv, att);
    // 5. attention out-proj
    hipLaunchKernelGGL(gemm_bf16, dim3(57, 4), b256, 0, stream,
                       att, outp_w, outp_b, tmp, NROW, 256, 256, 256, 0);
    // 6. tgt_a = LN2(tgt + tmp); xca = tgt_a + qpos (into xq buffer)
    hipLaunchKernelGGL(ln_resid, dim3(3600), b256, 0, stream,
                       tgt, tmp, ln2g, ln2b, tgt_a, qpos, xq);
    // 7. value = memory @ vproj^T + b
    hipLaunchKernelGGL(gemm_bf16, dim3(704, 4), b256, 0, stream,
                       mem, vp_w, vp_b, value, VROWS, 256, 256, 256, 0);
    // 8. sampling offsets
    hipLaunchKernelGGL(gemm_bf16, dim3(57, 4), b256, 0, stream,
                       xq, off_w, off_b, off_raw, NROW, 256, 256, 256, 0);
    // 9. attention-weight logits
    hipLaunchKernelGGL(gemm_bf16, dim3(57, 2), b256, 0, stream,
                       xq, aw_w, aw_b, aw_raw, NROW, 128, 256, 128, 0);
    // 10. deformable sampling -> att buffer (reused)
    hipLaunchKernelGGL(msdeform_kernel, dim3(3600), b256, 0, stream,
                       off_raw, aw_raw, refp, value, att);
    // 11. oproj
    hipLaunchKernelGGL(gemm_bf16, dim3(57, 4), b256, 0, stream,
                       att, op_w, op_b, tmp, NROW, 256, 256, 256, 0);
    // 12. tgt_b = LN1(tgt_a + tmp)
    hipLaunchKernelGGL(ln_resid, dim3(3600), b256, 0, stream,
                       tgt_a, tmp, ln1g, ln1b, tgt_b, (const float*)nullptr, (float*)nullptr);
    // 13. hidden = relu(tgt_b @ lin1^T + b)
    hipLaunchKernelGGL(gemm_bf16, dim3(57, 16), b256, 0, stream,
                       tgt_b, l1w, l1b, hidden, NROW, 1024, 256, 1024, 1);
    // 14. tmp = hidden @ lin2^T + b
    hipLaunchKernelGGL(gemm_bf16, dim3(57, 4), b256, 0, stream,
                       hidden, l2w, l2b, tmp, NROW, 256, 1024, 256, 0);
    // 15. out = LN3(tgt_b + tmp)
    hipLaunchKernelGGL(ln_resid, dim3(3600), b256, 0, stream,
                       tgt_b, tmp, ln3g, ln3b, out, (const float*)nullptr, (float*)nullptr);
}

// Round 4
// 322.425 us; speedup vs baseline: 1.8238x; 1.0030x over previous
//
#include <hip/hip_runtime.h>
#include <math.h>

#define D_MODEL 256
#define NHEAD   8
#define NLVL    4
#define NPTS    4
#define DHEAD   32
#define DFFN    1024
#define NQ      900
#define BSZ     4
#define NROW    (NQ * BSZ)      // 3600
#define S_TOT   11253
#define VROWS   (S_TOT * BSZ)   // 45012

typedef __attribute__((ext_vector_type(8))) short short8;
typedef __attribute__((ext_vector_type(4))) float f32x4;

static __device__ __forceinline__ unsigned f2bf1(float f) {
    unsigned u = __float_as_uint(f);
    return (u + 0x7FFFu + ((u >> 16) & 1u)) >> 16;
}
static __device__ __forceinline__ unsigned pack2bf(float x, float y) {
    return f2bf1(x) | (f2bf1(y) << 16);
}
static __device__ __forceinline__ float bf2f(unsigned short u) {
    return __uint_as_float(((unsigned)u) << 16);
}

// ---------------------------------------------------------------------------
// bf16 MFMA GEMM:  C[m,n] = sum_k A[m,k]*W[n,k] + bias[n]   (fp32 in/out)
// ---------------------------------------------------------------------------
#define GPAD 72

__global__ __launch_bounds__(256) void gemm_bf16(
    const float* __restrict__ A, const float* __restrict__ W,
    const float* __restrict__ bias, float* __restrict__ C,
    int M, int N, int K, int ldc, int relu)
{
    __shared__ unsigned short As[64 * GPAD];
    __shared__ unsigned short Ws[64 * GPAD];

    const int t  = threadIdx.x;
    const int m0 = blockIdx.x * 64;
    const int n0 = blockIdx.y * 64;

    const int trow = t >> 2;
    const int tk   = (t & 3) << 4;

    const int wv   = t >> 6;
    const int ln   = t & 63;
    const int mfr  = ln & 15;
    const int quad = ln >> 4;

    f32x4 acc[4] = {{0.f,0.f,0.f,0.f},{0.f,0.f,0.f,0.f},
                    {0.f,0.f,0.f,0.f},{0.f,0.f,0.f,0.f}};

    for (int k0 = 0; k0 < K; k0 += 64) {
        {
            int m = m0 + trow;
            float4 a0, a1, a2, a3;
            if (m < M) {
                const float* ap = A + (size_t)m * K + k0 + tk;
                a0 = *(const float4*)(ap + 0);
                a1 = *(const float4*)(ap + 4);
                a2 = *(const float4*)(ap + 8);
                a3 = *(const float4*)(ap + 12);
            } else {
                a0 = a1 = a2 = a3 = make_float4(0.f, 0.f, 0.f, 0.f);
            }
            uint4 u0, u1;
            u0.x = pack2bf(a0.x, a0.y); u0.y = pack2bf(a0.z, a0.w);
            u0.z = pack2bf(a1.x, a1.y); u0.w = pack2bf(a1.z, a1.w);
            u1.x = pack2bf(a2.x, a2.y); u1.y = pack2bf(a2.z, a2.w);
            u1.z = pack2bf(a3.x, a3.y); u1.w = pack2bf(a3.z, a3.w);
            *(uint4*)&As[trow * GPAD + tk + 0] = u0;
            *(uint4*)&As[trow * GPAD + tk + 8] = u1;
        }
        {
            int n = n0 + trow;
            const float* wp = W + (size_t)n * K + k0 + tk;
            float4 a0 = *(const float4*)(wp + 0);
            float4 a1 = *(const float4*)(wp + 4);
            float4 a2 = *(const float4*)(wp + 8);
            float4 a3 = *(const float4*)(wp + 12);
            uint4 u0, u1;
            u0.x = pack2bf(a0.x, a0.y); u0.y = pack2bf(a0.z, a0.w);
            u0.z = pack2bf(a1.x, a1.y); u0.w = pack2bf(a1.z, a1.w);
            u1.x = pack2bf(a2.x, a2.y); u1.y = pack2bf(a2.z, a2.w);
            u1.z = pack2bf(a3.x, a3.y); u1.w = pack2bf(a3.z, a3.w);
            *(uint4*)&Ws[trow * GPAD + tk + 0] = u0;
            *(uint4*)&Ws[trow * GPAD + tk + 8] = u1;
        }
        __syncthreads();

#pragma unroll
        for (int kh = 0; kh < 2; ++kh) {
            short8 af = *(const short8*)&As[(wv * 16 + mfr) * GPAD + kh * 32 + quad * 8];
#pragma unroll
            for (int cb = 0; cb < 4; ++cb) {
                short8 bf = *(const short8*)&Ws[(cb * 16 + mfr) * GPAD + kh * 32 + quad * 8];
                acc[cb] = __builtin_amdgcn_mfma_f32_16x16x32_bf16(af, bf, acc[cb], 0, 0, 0);
            }
        }
        __syncthreads();
    }

#pragma unroll
    for (int cb = 0; cb < 4; ++cb) {
        int col = n0 + cb * 16 + mfr;
        float bv = bias[col];
#pragma unroll
        for (int i = 0; i < 4; ++i) {
            int m = m0 + wv * 16 + quad * 4 + i;
            if (m < M) {
                float o = acc[cb][i] + bv;
                if (relu) o = fmaxf(o, 0.f);
                C[(size_t)m * ldc + col] = o;
            }
        }
    }
}

// ---------------------------------------------------------------------------
// Value projection, full-N blocking, bf16 output.
// C[m, 0:256] = bf16( sum_k A[m,k]*W[n,k] + bias[n] ).  K = N = 256.
// One block: 64 rows x 256 cols. A fetched exactly once; W is L2-resident.
// ---------------------------------------------------------------------------
__global__ __launch_bounds__(256) void vproj_bf16(
    const float* __restrict__ A, const float* __restrict__ W,
    const float* __restrict__ bias, unsigned short* __restrict__ C, int M)
{
    __shared__ unsigned short As[64 * GPAD];     // 4608 shorts
    __shared__ unsigned short Ws[256 * GPAD];    // 18432 shorts; reused as Cs[64][264]

    const int t  = threadIdx.x;
    const int m0 = blockIdx.x * 64;

    const int trow = t >> 2;
    const int tk   = (t & 3) << 4;

    const int wv   = t >> 6;
    const int ln   = t & 63;
    const int L    = ln & 15;
    const int quad = ln >> 4;

    f32x4 acc[16];
#pragma unroll
    for (int i = 0; i < 16; ++i) acc[i] = (f32x4){0.f, 0.f, 0.f, 0.f};

    for (int k0 = 0; k0 < 256; k0 += 64) {
        // ---- stage A tile (64 x 64), M-guarded ----
        {
            int m = m0 + trow;
            float4 a0, a1, a2, a3;
            if (m < M) {
                const float* ap = A + (size_t)m * 256 + k0 + tk;
                a0 = *(const float4*)(ap + 0);
                a1 = *(const float4*)(ap + 4);
                a2 = *(const float4*)(ap + 8);
                a3 = *(const float4*)(ap + 12);
            } else {
                a0 = a1 = a2 = a3 = make_float4(0.f, 0.f, 0.f, 0.f);
            }
            uint4 u0, u1;
            u0.x = pack2bf(a0.x, a0.y); u0.y = pack2bf(a0.z, a0.w);
            u0.z = pack2bf(a1.x, a1.y); u0.w = pack2bf(a1.z, a1.w);
            u1.x = pack2bf(a2.x, a2.y); u1.y = pack2bf(a2.z, a2.w);
            u1.z = pack2bf(a3.x, a3.y); u1.w = pack2bf(a3.z, a3.w);
            *(uint4*)&As[trow * GPAD + tk + 0] = u0;
            *(uint4*)&As[trow * GPAD + tk + 8] = u1;
        }
        // ---- stage W tile (256 x 64) ----
#pragma unroll
        for (int wb = 0; wb < 4; ++wb) {
            int n = wb * 64 + trow;
            const float* wp = W + (size_t)n * 256 + k0 + tk;
            float4 a0 = *(const float4*)(wp + 0);
            float4 a1 = *(const float4*)(wp + 4);
            float4 a2 = *(const float4*)(wp + 8);
            float4 a3 = *(const float4*)(wp + 12);
            uint4 u0, u1;
            u0.x = pack2bf(a0.x, a0.y); u0.y = pack2bf(a0.z, a0.w);
            u0.z = pack2bf(a1.x, a1.y); u0.w = pack2bf(a1.z, a1.w);
            u1.x = pack2bf(a2.x, a2.y); u1.y = pack2bf(a2.z, a2.w);
            u1.z = pack2bf(a3.x, a3.y); u1.w = pack2bf(a3.z, a3.w);
            *(uint4*)&Ws[n * GPAD + tk + 0] = u0;
            *(uint4*)&Ws[n * GPAD + tk + 8] = u1;
        }
        __syncthreads();

#pragma unroll
        for (int kh = 0; kh < 2; ++kh) {
            short8 af = *(const short8*)&As[(wv * 16 + L) * GPAD + kh * 32 + quad * 8];
#pragma unroll
            for (int cb = 0; cb < 16; ++cb) {
                short8 bf = *(const short8*)&Ws[(cb * 16 + L) * GPAD + kh * 32 + quad * 8];
                acc[cb] = __builtin_amdgcn_mfma_f32_16x16x32_bf16(af, bf, acc[cb], 0, 0, 0);
            }
        }
        __syncthreads();
    }

    // ---- epilogue: bias + bf16, repack through LDS for coalesced stores ----
    unsigned short* Cs = Ws;   // 64 rows x 264 stride = 16896 shorts (fits)
#pragma unroll
    for (int cb = 0; cb < 16; ++cb) {
        int col = cb * 16 + L;
        float bv = bias[col];
#pragma unroll
        for (int i = 0; i < 4; ++i) {
            int r = wv * 16 + quad * 4 + i;
            Cs[r * 264 + col] = (unsigned short)f2bf1(acc[cb][i] + bv);
        }
    }
    __syncthreads();
    {
        int r  = t >> 2;
        int ch = (t & 3) * 64;
        int m  = m0 + r;
        if (m < M) {
            const unsigned short* src = &Cs[r * 264 + ch];
            uint4* dst = (uint4*)(C + (size_t)m * 256 + ch);
#pragma unroll
            for (int j = 0; j < 8; ++j)
                dst[j] = *(const uint4*)(src + j * 8);
        }
    }
}

// ---------------------------------------------------------------------------
// Elementwise add
// ---------------------------------------------------------------------------
__global__ void add_vec(const float* __restrict__ a, const float* __restrict__ b,
                        float* __restrict__ c, int n4)
{
    int i = blockIdx.x * blockDim.x + threadIdx.x;
    if (i < n4) {
        float4 x = ((const float4*)a)[i];
        float4 y = ((const float4*)b)[i];
        float4 z;
        z.x = x.x + y.x; z.y = x.y + y.y; z.z = x.z + y.z; z.w = x.w + y.w;
        ((float4*)c)[i] = z;
    }
}

// ---------------------------------------------------------------------------
// MFMA flash self-attention (unchanged from round 3).
// ---------------------------------------------------------------------------
__global__ __launch_bounds__(256) void sa_flash(
    const float* __restrict__ qkv, float* __restrict__ attn_out)
{
    __shared__ unsigned short Ks[2 * 2080];
    __shared__ unsigned short Vt[2 * 2304];
    __shared__ unsigned short Ps[4 * 1152];

    const int t    = threadIdx.x;
    const int q0   = blockIdx.x * 64;
    const int b    = blockIdx.y & 3;
    const int h    = blockIdx.y >> 2;
    const int wv   = t >> 6;
    const int ln   = t & 63;
    const int L    = ln & 15;
    const int quad = ln >> 4;

    const float scale = 0.17677669529663687f;

    union { uint4 u; short8 s; } qu;
    qu.u = make_uint4(0u, 0u, 0u, 0u);
    {
        int q = q0 + wv * 16 + L;
        if (q < NQ) {
            const float* qp = qkv + ((size_t)q * 4 + b) * 768 + h * 32 + quad * 8;
            float4 f0 = *(const float4*)qp;
            float4 f1 = *(const float4*)(qp + 4);
            qu.u.x = pack2bf(f0.x * scale, f0.y * scale);
            qu.u.y = pack2bf(f0.z * scale, f0.w * scale);
            qu.u.z = pack2bf(f1.x * scale, f1.y * scale);
            qu.u.w = pack2bf(f1.z * scale, f1.w * scale);
        }
    }
    const short8 qf = qu.s;

    float mrun = -1e30f, lrun = 0.f;
    f32x4 oacc[2] = {{0.f,0.f,0.f,0.f},{0.f,0.f,0.f,0.f}};

    const int skey = t >> 2;
    const int sdg  = t & 3;

    int it = 0;
    for (int k0 = 0; k0 < NQ; k0 += 64, it ^= 1) {
        {
            int kg = k0 + skey;
            float4 f0, f1, g0, g1;
            if (kg < NQ) {
                const float* kp = qkv + ((size_t)kg * 4 + b) * 768 + 256 + h * 32 + sdg * 8;
                f0 = *(const float4*)kp;
                f1 = *(const float4*)(kp + 4);
                g0 = *(const float4*)(kp + 256);
                g1 = *(const float4*)(kp + 260);
            } else {
                f0 = f1 = g0 = g1 = make_float4(0.f, 0.f, 0.f, 0.f);
            }
            uint4 ku;
            ku.x = pack2bf(f0.x, f0.y); ku.y = pack2bf(f0.z, f0.w);
            ku.z = pack2bf(f1.x, f1.y); ku.w = pack2bf(f1.z, f1.w);
            *(uint4*)&Ks[it * 2080 + sdg * 520 + skey * 8] = ku;
            unsigned short* vp = &Vt[it * 2304 + sdg * 8 * 72 + skey];
            vp[0 * 72] = (unsigned short)f2bf1(g0.x);
            vp[1 * 72] = (unsigned short)f2bf1(g0.y);
            vp[2 * 72] = (unsigned short)f2bf1(g0.z);
            vp[3 * 72] = (unsigned short)f2bf1(g0.w);
            vp[4 * 72] = (unsigned short)f2bf1(g1.x);
            vp[5 * 72] = (unsigned short)f2bf1(g1.y);
            vp[6 * 72] = (unsigned short)f2bf1(g1.z);
            vp[7 * 72] = (unsigned short)f2bf1(g1.w);
        }
        __syncthreads();

        f32x4 sacc[4] = {{0.f,0.f,0.f,0.f},{0.f,0.f,0.f,0.f},
                         {0.f,0.f,0.f,0.f},{0.f,0.f,0.f,0.f}};
#pragma unroll
        for (int cb = 0; cb < 4; ++cb) {
            short8 kf = *(const short8*)&Ks[it * 2080 + quad * 520 + (cb * 16 + L) * 8];
            sacc[cb] = __builtin_amdgcn_mfma_f32_16x16x32_bf16(kf, qf, sacc[cb], 0, 0, 0);
        }
        if (k0 + 64 > NQ) {
#pragma unroll
            for (int cb = 0; cb < 4; ++cb)
#pragma unroll
                for (int i = 0; i < 4; ++i)
                    if (k0 + cb * 16 + quad * 4 + i >= NQ) sacc[cb][i] = -1e30f;
        }

        float ml = -1e30f;
#pragma unroll
        for (int cb = 0; cb < 4; ++cb)
#pragma unroll
            for (int i = 0; i < 4; ++i) ml = fmaxf(ml, sacc[cb][i]);
        ml = fmaxf(ml, __shfl_xor(ml, 16, 64));
        ml = fmaxf(ml, __shfl_xor(ml, 32, 64));
        float mnew  = fmaxf(mrun, ml);
        float alpha = __expf(mrun - mnew);
        float p[16];
        float rs = 0.f;
#pragma unroll
        for (int cb = 0; cb < 4; ++cb)
#pragma unroll
            for (int i = 0; i < 4; ++i) {
                float e = __expf(sacc[cb][i] - mnew);
                p[cb * 4 + i] = e;
                rs += e;
            }
        rs += __shfl_xor(rs, 16, 64);
        rs += __shfl_xor(rs, 32, 64);
        lrun = lrun * alpha + rs;
        mrun = mnew;

        {
            unsigned short* pw = &Ps[wv * 1152 + L * 72];
#pragma unroll
            for (int cb = 0; cb < 4; ++cb) {
                uint2 u;
                u.x = pack2bf(p[cb * 4 + 0], p[cb * 4 + 1]);
                u.y = pack2bf(p[cb * 4 + 2], p[cb * 4 + 3]);
                *(uint2*)&pw[cb * 16 + quad * 4] = u;
            }
        }
#pragma unroll
        for (int i = 0; i < 4; ++i) {
            float ai = __shfl(alpha, quad * 4 + i, 64);
            oacc[0][i] *= ai;
            oacc[1][i] *= ai;
        }
        __syncthreads();

#pragma unroll
        for (int ks = 0; ks < 2; ++ks) {
            short8 pf = *(const short8*)&Ps[wv * 1152 + L * 72 + ks * 32 + quad * 8];
#pragma unroll
            for (int db = 0; db < 2; ++db) {
                short8 vf = *(const short8*)&Vt[it * 2304 + (db * 16 + L) * 72 + ks * 32 + quad * 8];
                oacc[db] = __builtin_amdgcn_mfma_f32_16x16x32_bf16(pf, vf, oacc[db], 0, 0, 0);
            }
        }
    }

#pragma unroll
    for (int i = 0; i < 4; ++i) {
        float lq = __shfl(lrun, quad * 4 + i, 64);
        float li = 1.f / lq;
        int q = q0 + wv * 16 + quad * 4 + i;
        if (q < NQ) {
            float* op = attn_out + ((size_t)q * 4 + b) * 256 + h * 32 + L;
            op[0]  = oacc[0][i] * li;
            op[16] = oacc[1][i] * li;
        }
    }
}

// ---------------------------------------------------------------------------
// Residual + LayerNorm (optionally also emits y + pos into out2).
// ---------------------------------------------------------------------------
__global__ __launch_bounds__(256) void ln_resid(
    const float* __restrict__ xa, const float* __restrict__ xb,
    const float* __restrict__ gam, const float* __restrict__ bet,
    float* __restrict__ out, const float* __restrict__ pos, float* __restrict__ out2)
{
    const int row = blockIdx.x;
    const int t = threadIdx.x;
    float x = xa[(size_t)row * D_MODEL + t] + xb[(size_t)row * D_MODEL + t];
    float s = x, s2 = x * x;
#pragma unroll
    for (int off = 32; off > 0; off >>= 1) {
        s  += __shfl_down(s, off, 64);
        s2 += __shfl_down(s2, off, 64);
    }
    __shared__ float rs[4], rs2[4];
    __shared__ float mean_s, rstd_s;
    int wid = t >> 6, lane = t & 63;
    if (lane == 0) { rs[wid] = s; rs2[wid] = s2; }
    __syncthreads();
    if (t == 0) {
        float S = rs[0] + rs[1] + rs[2] + rs[3];
        float S2 = rs2[0] + rs2[1] + rs2[2] + rs2[3];
        float mean = S * (1.f / 256.f);
        float var = S2 * (1.f / 256.f) - mean * mean;
        mean_s = mean;
        rstd_s = rsqrtf(var + 1e-5f);
    }
    __syncthreads();
    float y = (x - mean_s) * rstd_s * gam[t] + bet[t];
    out[(size_t)row * D_MODEL + t] = y;
    if (out2) out2[(size_t)row * D_MODEL + t] = y + pos[(size_t)row * D_MODEL + t];
}

// ---------------------------------------------------------------------------
// Multi-scale deformable sampling (value is bf16 now).
// ---------------------------------------------------------------------------
__global__ __launch_bounds__(256) void msdeform_kernel(
    const float* __restrict__ off_raw, const float* __restrict__ aw_raw,
    const float* __restrict__ refp, const unsigned short* __restrict__ value,
    float* __restrict__ out)
{
    const int row = blockIdx.x;   // q*4+b
    const int b = row & 3;
    const int t = threadIdx.x;

    __shared__ float aw_s[8][17];
    __shared__ float px_s[8][16];
    __shared__ float py_s[8][16];

    const int Hs[4]  = {92, 46, 23, 12};
    const int Wd[4]  = {92, 46, 23, 12};
    const int S0_[4] = {0, 8464, 10580, 11109};

    if (t < 128) {
        int hh = t >> 4, lp = t & 15, l = lp >> 2;
        float ox = off_raw[(size_t)row * 256 + hh * 32 + lp * 2 + 0];
        float oy = off_raw[(size_t)row * 256 + hh * 32 + lp * 2 + 1];
        float rx = refp[((size_t)row * 4 + l) * 2 + 0];
        float ry = refp[((size_t)row * 4 + l) * 2 + 1];
        px_s[hh][lp] = rx * (float)Wd[l] + ox - 0.5f;
        py_s[hh][lp] = ry * (float)Hs[l] + oy - 0.5f;
    }
    if (t < 8) {
        int hh = t;
        float v[16];
        float m = -1e30f;
#pragma unroll
        for (int j = 0; j < 16; ++j) {
            v[j] = aw_raw[(size_t)row * 128 + hh * 16 + j];
            m = fmaxf(m, v[j]);
        }
        float ssum = 0.f;
#pragma unroll
        for (int j = 0; j < 16; ++j) { v[j] = __expf(v[j] - m); ssum += v[j]; }
        float inv = 1.f / ssum;
#pragma unroll
        for (int j = 0; j < 16; ++j) aw_s[hh][j] = v[j] * inv;
    }
    __syncthreads();

    const int h = t >> 5, d = t & 31;
    const unsigned short* vb = value + (size_t)b * 256 + h * 32 + d;
    float acc = 0.f;
#pragma unroll
    for (int l = 0; l < 4; ++l) {
        const int H = Hs[l], W = Wd[l], base = S0_[l];
#pragma unroll
        for (int p = 0; p < 4; ++p) {
            const int lp = l * 4 + p;
            float px = px_s[h][lp], py = py_s[h][lp];
            float x0f = floorf(px), y0f = floorf(py);
            int x0 = (int)x0f, y0 = (int)y0f;
            float wx = px - x0f, wy = py - y0f;
            float sv = 0.f;
#pragma unroll
            for (int dy = 0; dy < 2; ++dy) {
#pragma unroll
                for (int dx = 0; dx < 2; ++dx) {
                    int xi = x0 + dx, yi = y0 + dy;
                    float flag = (xi >= 0 && xi < W && yi >= 0 && yi < H) ? 1.f : 0.f;
                    int xc = xi < 0 ? 0 : (xi >= W ? W - 1 : xi);
                    int yc = yi < 0 ? 0 : (yi >= H ? H - 1 : yi);
                    float wgt = (dx ? wx : 1.f - wx) * (dy ? wy : 1.f - wy);
                    float gv = bf2f(vb[(size_t)(base + yc * W + xc) * 1024]);
                    sv = fmaf(wgt * flag, gv, sv);
                }
            }
            acc = fmaf(aw_s[h][lp], sv, acc);
        }
    }
    out[(size_t)row * 256 + h * 32 + d] = acc;
}

// ---------------------------------------------------------------------------
extern "C" void kernel_launch(void* const* d_in, const int* in_sizes, int n_in,
                              void* d_out, int out_size, void* d_ws, size_t ws_size,
                              hipStream_t stream)
{
    const float* tgt    = (const float*)d_in[0];
    const float* qpos   = (const float*)d_in[1];
    const float* refp   = (const float*)d_in[2];
    const float* mem    = (const float*)d_in[3];
    const float* in_w   = (const float*)d_in[6];
    const float* in_b   = (const float*)d_in[7];
    const float* outp_w = (const float*)d_in[8];
    const float* outp_b = (const float*)d_in[9];
    const float* off_w  = (const float*)d_in[10];
    const float* off_b  = (const float*)d_in[11];
    const float* aw_w   = (const float*)d_in[12];
    const float* aw_b   = (const float*)d_in[13];
    const float* vp_w   = (const float*)d_in[14];
    const float* vp_b   = (const float*)d_in[15];
    const float* op_w   = (const float*)d_in[16];
    const float* op_b   = (const float*)d_in[17];
    const float* ln1g   = (const float*)d_in[18];
    const float* ln1b   = (const float*)d_in[19];
    const float* ln2g   = (const float*)d_in[20];
    const float* ln2b   = (const float*)d_in[21];
    const float* ln3g   = (const float*)d_in[22];
    const float* ln3b   = (const float*)d_in[23];
    const float* l1w    = (const float*)d_in[24];
    const float* l1b    = (const float*)d_in[25];
    const float* l2w    = (const float*)d_in[26];
    const float* l2b    = (const float*)d_in[27];
    float* out = (float*)d_out;
    float* ws  = (float*)d_ws;

    float* qkv     = ws;                 // 3600*768
    float* off_raw = ws;                 // reuse of qkv region (after SA done)
    float* aw_raw  = ws + 921600;
    float* xq      = ws + 2764800;
    float* att     = ws + 3686400;
    float* tmp     = ws + 4608000;
    float* tgt_a   = ws + 5529600;
    float* tgt_b   = ws + 6451200;
    unsigned short* value = (unsigned short*)(ws + 7372800);  // 45012*256 bf16
    float* hidden  = ws + 7372800;       // reuse region after sampling (3600*1024 fp32)

    dim3 b256(256);

    // 1. xq = tgt + qpos
    hipLaunchKernelGGL(add_vec, dim3(900), b256, 0, stream, tgt, qpos, xq, 230400);
    // 2. qkv[:, 0:512] = xq @ [wq;wk]^T + b
    hipLaunchKernelGGL(gemm_bf16, dim3(57, 8), b256, 0, stream,
                       xq, in_w, in_b, qkv, NROW, 512, 256, 768, 0);
    // 3. qkv[:, 512:768] = tgt @ wv^T + bv
    hipLaunchKernelGGL(gemm_bf16, dim3(57, 4), b256, 0, stream,
                       tgt, in_w + 512 * 256, in_b + 512, qkv + 512, NROW, 256, 256, 768, 0);
    // 4. flash self-attention
    hipLaunchKernelGGL(sa_flash, dim3(15, 32), b256, 0, stream, qkv, att);
    // 5. attention out-proj
    hipLaunchKernelGGL(gemm_bf16, dim3(57, 4), b256, 0, stream,
                       att, outp_w, outp_b, tmp, NROW, 256, 256, 256, 0);
    // 6. tgt_a = LN2(tgt + tmp); xca = tgt_a + qpos (into xq buffer)
    hipLaunchKernelGGL(ln_resid, dim3(3600), b256, 0, stream,
                       tgt, tmp, ln2g, ln2b, tgt_a, qpos, xq);
    // 7. value = bf16(memory @ vproj^T + b)  — full-N blocking, A fetched once
    hipLaunchKernelGGL(vproj_bf16, dim3(704), b256, 0, stream,
                       mem, vp_w, vp_b, value, VROWS);
    // 8. sampling offsets
    hipLaunchKernelGGL(gemm_bf16, dim3(57, 4), b256, 0, stream,
                       xq, off_w, off_b, off_raw, NROW, 256, 256, 256, 0);
    // 9. attention-weight logits
    hipLaunchKernelGGL(gemm_bf16, dim3(57, 2), b256, 0, stream,
                       xq, aw_w, aw_b, aw_raw, NROW, 128, 256, 128, 0);
    // 10. deformable sampling -> att buffer (reused)
    hipLaunchKernelGGL(msdeform_kernel, dim3(3600), b256, 0, stream,
                       off_raw, aw_raw, refp, value, att);
    // 11. oproj
    hipLaunchKernelGGL(gemm_bf16, dim3(57, 4), b256, 0, stream,
                       att, op_w, op_b, tmp, NROW, 256, 256, 256, 0);
    // 12. tgt_b = LN1(tgt_a + tmp)
    hipLaunchKernelGGL(ln_resid, dim3(3600), b256, 0, stream,
                       tgt_a, tmp, ln1g, ln1b, tgt_b, (const float*)nullptr, (float*)nullptr);
    // 13. hidden = relu(tgt_b @ lin1^T + b)
    hipLaunchKernelGGL(gemm_bf16, dim3(57, 16), b256, 0, stream,
                       tgt_b, l1w, l1b, hidden, NROW, 1024, 256, 1024, 1);
    // 14. tmp = hidden @ lin2^T + b
    hipLaunchKernelGGL(gemm_bf16, dim3(57, 4), b256, 0, stream,
                       hidden, l2w, l2b, tmp, NROW, 256, 1024, 256, 0);
    // 15. out = LN3(tgt_b + tmp)
    hipLaunchKernelGGL(ln_resid, dim3(3600), b256, 0, stream,
                       tgt_b, tmp, ln3g, ln3b, out, (const float*)nullptr, (float*)nullptr);
}